// Round 4
// baseline (170.694 us; speedup 1.0000x reference)
//
#include <hip/hip_runtime.h>

// Sparse generative transposed-conv LSTM decoder (3 timesteps).
// R4: barrier-free step kernel. No LDS: each lane gathers its MFMA A-fragment
// directly from global (L1 absorbs the 4x cross-wave redundancy), weights stay
// register-resident per bucket, manual 1-tile-deep register prefetch, h/c
// interleaved per row. 6 dispatches (memset, prep+count, scatter, 3 steps).

#define KNUM 8
#define TM 16           // rows per tile (one 16x16 MFMA row-block)
#define STEP_THREADS 256

typedef __attribute__((ext_vector_type(8))) _Float16 f16x8;
typedef __attribute__((ext_vector_type(4))) float f32x4;

__device__ __forceinline__ float fsig(float x) {
  return __builtin_amdgcn_rcpf(1.0f + __expf(-x));
}
__device__ __forceinline__ float ftanh_(float x) {
  float e = __expf(2.0f * x);
  return 1.0f - 2.0f * __builtin_amdgcn_rcpf(e + 1.0f);
}
__device__ __forceinline__ f16x8 to_h8(float4 a, float4 b) {
  f16x8 r;
  r[0] = (_Float16)a.x; r[1] = (_Float16)a.y; r[2] = (_Float16)a.z; r[3] = (_Float16)a.w;
  r[4] = (_Float16)b.x; r[5] = (_Float16)b.y; r[6] = (_Float16)b.z; r[7] = (_Float16)b.w;
  return r;
}

// ---- prep: transpose+cast weights, cast x inputs to f16, histogram kofs ----
__global__ void prep_kernel(const float* __restrict__ Wi, const float* __restrict__ Wh,
                            const float* __restrict__ Wc,
                            const float* __restrict__ x0, const float* __restrict__ x1,
                            const float* __restrict__ x2, int ne0, int ne1, int ne2,
                            const int* __restrict__ k0, int n0,
                            const int* __restrict__ k1, int n1,
                            const int* __restrict__ k2, int n2,
                            _Float16* __restrict__ WgT, _Float16* __restrict__ WcT,
                            _Float16* __restrict__ x0f, _Float16* __restrict__ x1f,
                            _Float16* __restrict__ x2f, int* __restrict__ counts) {
  __shared__ int sh[3 * KNUM];
  if (threadIdx.x < 3 * KNUM) sh[threadIdx.x] = 0;
  __syncthreads();
  int tid = blockIdx.x * blockDim.x + threadIdx.x;
  int stride = gridDim.x * blockDim.x;
  // WgT[k][co][ci]: ci<64 -> W_h, else W_i (transposed, f16)
  for (int idx = tid; idx < KNUM * 256 * 128; idx += stride) {
    int k  = idx >> 15;
    int co = (idx >> 7) & 255;
    int ci = idx & 127;
    float v = (ci < 64) ? Wh[(k * 64 + ci) * 256 + co]
                        : Wi[(k * 64 + ci - 64) * 256 + co];
    WgT[idx] = (_Float16)v;
  }
  for (int idx = tid; idx < KNUM * 64 * 64; idx += stride) {
    int k  = idx >> 12;
    int co = (idx >> 6) & 63;
    int ci = idx & 63;
    WcT[idx] = (_Float16)Wc[(k * 64 + ci) * 64 + co];
  }
  for (int i = tid; i < (ne0 >> 3); i += stride) {
    float4 a = ((const float4*)x0)[2 * i], b = ((const float4*)x0)[2 * i + 1];
    ((f16x8*)x0f)[i] = to_h8(a, b);
  }
  for (int i = tid; i < (ne1 >> 3); i += stride) {
    float4 a = ((const float4*)x1)[2 * i], b = ((const float4*)x1)[2 * i + 1];
    ((f16x8*)x1f)[i] = to_h8(a, b);
  }
  for (int i = tid; i < (ne2 >> 3); i += stride) {
    float4 a = ((const float4*)x2)[2 * i], b = ((const float4*)x2)[2 * i + 1];
    ((f16x8*)x2f)[i] = to_h8(a, b);
  }
  // histograms (counts pre-zeroed by memset)
  for (int i = tid; i < n0; i += stride) atomicAdd(&sh[k0[i]], 1);
  for (int i = tid; i < n1; i += stride) atomicAdd(&sh[KNUM + k1[i]], 1);
  for (int i = tid; i < n2; i += stride) atomicAdd(&sh[2 * KNUM + k2[i]], 1);
  __syncthreads();
  if (threadIdx.x < 3 * KNUM && sh[threadIdx.x]) atomicAdd(&counts[threadIdx.x], sh[threadIdx.x]);
}

// ---- scatter (order + porder), offsets from counts, cursor pre-zeroed ----
__device__ __forceinline__ void seg_select(int b, int& seg, int& rb, int& nb) {
  if (b < 32)       { seg = 0; rb = b;       nb = 32;  }
  else if (b < 160) { seg = 1; rb = b - 32;  nb = 128; }
  else              { seg = 2; rb = b - 160; nb = 352; }
}

__global__ void scatter_all_kernel(const int* __restrict__ k0, const int* __restrict__ p0, int n0,
                                   int* __restrict__ o0, int* __restrict__ q0,
                                   const int* __restrict__ k1, const int* __restrict__ p1, int n1,
                                   int* __restrict__ o1, int* __restrict__ q1,
                                   const int* __restrict__ k2, const int* __restrict__ p2, int n2,
                                   int* __restrict__ o2, int* __restrict__ q2,
                                   const int* __restrict__ counts, int* __restrict__ cursor) {
  int seg, rb, nb;
  seg_select(blockIdx.x, seg, rb, nb);
  const int* kp = seg == 0 ? k0 : seg == 1 ? k1 : k2;
  const int* pp = seg == 0 ? p0 : seg == 1 ? p1 : p2;
  int n = seg == 0 ? n0 : seg == 1 ? n1 : n2;
  int* order  = seg == 0 ? o0 : seg == 1 ? o1 : o2;
  int* porder = seg == 0 ? q0 : seg == 1 ? q1 : q2;

  __shared__ int h[KNUM], base[KNUM];
  if (threadIdx.x < KNUM) h[threadIdx.x] = 0;
  __syncthreads();
  int chunk = (n + nb - 1) / nb;
  int c0 = rb * chunk;
  int c1 = min(n, c0 + chunk);
  for (int i = c0 + threadIdx.x; i < c1; i += blockDim.x)
    atomicAdd(&h[kp[i]], 1);
  __syncthreads();
  if (threadIdx.x < KNUM) {
    int offk = 0;
    for (int k = 0; k < (int)threadIdx.x; ++k) offk += counts[seg * KNUM + k];
    base[threadIdx.x] = offk + atomicAdd(&cursor[seg * KNUM + threadIdx.x], h[threadIdx.x]);
    h[threadIdx.x] = 0;
  }
  __syncthreads();
  for (int i = c0 + threadIdx.x; i < c1; i += blockDim.x) {
    int k = kp[i];
    int pos = base[k] + atomicAdd(&h[k], 1);
    order[pos] = i;          // bucket order nondeterministic; output row-indexed -> deterministic
    porder[pos] = pp[i];
  }
}

// ---- barrier-free fused step kernel ----
// 256 threads = 4 waves; wave w owns 16-channel slice wc=w. All 4 waves walk
// the same tile stream (L1 reuse of A gathers) but never synchronize.
// hc layout: row j = [h(64 f16) | c(64 f16)], 256 B.
template <bool FIRST, bool LAST>
__global__ __launch_bounds__(STEP_THREADS)
void lstm_step_kernel(const _Float16* __restrict__ xf, const _Float16* __restrict__ hc_in,
                      const int* __restrict__ order, const int* __restrict__ porder,
                      const int* __restrict__ counts,
                      const _Float16* __restrict__ WgT, const _Float16* __restrict__ WcT,
                      float* __restrict__ out32, _Float16* __restrict__ hc_out, int bpk) {
  constexpr int NKS = FIRST ? 2 : 4;

  const int kb = blockIdx.x & 7;
  const int bi = blockIdx.x >> 3;
  int cnt = 0, off = 0;
#pragma unroll
  for (int k = 0; k < KNUM; ++k) {
    int c = counts[k];
    if (k < kb) off += c;
    if (k == kb) cnt = c;
  }
  const int ntiles = (cnt + TM - 1) / TM;
  if (bi >= ntiles) return;

  const int lane = threadIdx.x & 63;
  const int wc   = threadIdx.x >> 6;   // 16-channel slice
  const int l15  = lane & 15;
  const int kg   = lane >> 4;

  // B fragments in registers, once per block
  f16x8 bg[4][NKS];
  f16x8 bc[2];
  {
    const _Float16* wgp = WgT + (size_t)kb * (256 * 128) + kg * 8 + (FIRST ? 64 : 0);
#pragma unroll
    for (int g = 0; g < 4; ++g)
#pragma unroll
      for (int s = 0; s < NKS; ++s)
        bg[g][s] = *(const f16x8*)(wgp + (size_t)(64 * g + 16 * wc + l15) * 128 + s * 32);
    if constexpr (!FIRST) {
      const _Float16* wcp = WcT + (size_t)kb * (64 * 64) + kg * 8;
#pragma unroll
      for (int s = 0; s < 2; ++s)
        bc[s] = *(const f16x8*)(wcp + (size_t)(16 * wc + l15) * 64 + s * 32);
    }
  }

  // per-tile index + fragment loaders (clamped; stores guarded by j<0)
  auto idx_of = [&](int t, int& p, int* j) {
    int tt = min(t, ntiles - 1);
    int base = tt * TM;
    p = porder[off + min(base + l15, cnt - 1)];
#pragma unroll
    for (int r = 0; r < 4; ++r) {
      int grow = base + kg * 4 + r;
      j[r] = (t < ntiles && grow < cnt) ? order[off + grow] : -1;
    }
  };
  auto frags_of = [&](int p, f16x8* fx, f16x8* fh, f16x8* fc) {
    const _Float16* xr = xf + (size_t)p * 64 + kg * 8;
    fx[0] = *(const f16x8*)(xr);
    fx[1] = *(const f16x8*)(xr + 32);
    if constexpr (!FIRST) {
      const _Float16* hr = hc_in + (size_t)p * 128 + kg * 8;
      fh[0] = *(const f16x8*)(hr);
      fh[1] = *(const f16x8*)(hr + 32);
      fc[0] = *(const f16x8*)(hr + 64);
      fc[1] = *(const f16x8*)(hr + 96);
    }
  };

  int pc, jc[4], pn, jn[4];
  f16x8 cfx[2], cfh[2], cfc[2];
  f16x8 nfx[2], nfh[2], nfc[2];

  idx_of(bi, pc, jc);
  frags_of(pc, cfx, cfh, cfc);

  for (int t = bi; t < ntiles; t += bpk) {
    // prefetch next tile (indices + fragments) — flies under this tile's MFMA+epilogue
    idx_of(t + bpk, pn, jn);
    frags_of(pn, nfx, nfh, nfc);

    // MFMA: gates [16 rows x 64 ch slice... this wave: 16 ch], c_up
    f32x4 aG[4];
    f32x4 aC;
#pragma unroll
    for (int g = 0; g < 4; ++g) aG[g] = f32x4{0.f, 0.f, 0.f, 0.f};
    aC = f32x4{0.f, 0.f, 0.f, 0.f};
#pragma unroll
    for (int s = 0; s < NKS; ++s) {
      f16x8 a;
      if constexpr (FIRST) a = cfx[s];
      else a = (s < 2) ? cfh[s] : cfx[s - 2];
      aG[0] = __builtin_amdgcn_mfma_f32_16x16x32_f16(a, bg[0][s], aG[0], 0, 0, 0);
      aG[1] = __builtin_amdgcn_mfma_f32_16x16x32_f16(a, bg[1][s], aG[1], 0, 0, 0);
      aG[2] = __builtin_amdgcn_mfma_f32_16x16x32_f16(a, bg[2][s], aG[2], 0, 0, 0);
      aG[3] = __builtin_amdgcn_mfma_f32_16x16x32_f16(a, bg[3][s], aG[3], 0, 0, 0);
    }
    if constexpr (!FIRST) {
      aC = __builtin_amdgcn_mfma_f32_16x16x32_f16(cfc[0], bc[0], aC, 0, 0, 0);
      aC = __builtin_amdgcn_mfma_f32_16x16x32_f16(cfc[1], bc[1], aC, 0, 0, 0);
    }

    // LSTM epilogue + scatter store (C/D: row=kg*4+r, col=l15)
#pragma unroll
    for (int r = 0; r < 4; ++r) {
      int j = jc[r];
      if (j < 0) continue;
      float ing = fsig(aG[0][r]);
      float fg  = fsig(aG[1][r]);
      float cgt = fsig(aG[2][r]);   // reference uses sigmoid for cell gate
      float og  = fsig(aG[3][r]);
      float cup = FIRST ? 0.0f : aC[r];
      float cxv = fg * cup + ing * cgt;
      float hxv = og * ftanh_(cxv);
      int ch = 16 * wc + l15;
      if constexpr (LAST) {
        out32[(size_t)j * 64 + ch] = hxv;
      } else {
        hc_out[(size_t)j * 128 + ch]      = (_Float16)hxv;
        hc_out[(size_t)j * 128 + 64 + ch] = (_Float16)cxv;
      }
    }

    // rotate pipeline registers
    pc = pn;
#pragma unroll
    for (int r = 0; r < 4; ++r) jc[r] = jn[r];
#pragma unroll
    for (int s = 0; s < 2; ++s) {
      cfx[s] = nfx[s];
      if constexpr (!FIRST) { cfh[s] = nfh[s]; cfc[s] = nfc[s]; }
    }
  }
}

static inline int idiv_up(int a, int b) { return (a + b - 1) / b; }

template <bool FIRST, bool LAST>
static void run_step(const _Float16* xf, const _Float16* hc_in,
                     const int* order, const int* porder, int nout, const int* counts,
                     const _Float16* WgT, const _Float16* WcT,
                     float* out32, _Float16* hc_out, hipStream_t stream) {
  int bpk = idiv_up(nout, KNUM * TM);
  if (bpk > 128) bpk = 128;
  if (bpk < 1) bpk = 1;
  lstm_step_kernel<FIRST, LAST><<<dim3(KNUM * bpk), dim3(STEP_THREADS), 0, stream>>>(
      xf, hc_in, order, porder, counts, WgT, WcT, out32, hc_out, bpk);
}

extern "C" void kernel_launch(void* const* d_in, const int* in_sizes, int n_in,
                              void* d_out, int out_size, void* d_ws, size_t ws_size,
                              hipStream_t stream) {
  const float* x0 = (const float*)d_in[0];
  const float* x1 = (const float*)d_in[1];
  const float* x2 = (const float*)d_in[2];
  const float* Wi = (const float*)d_in[3];
  const float* Wh = (const float*)d_in[4];
  const float* Wc = (const float*)d_in[5];
  const int* parent0 = (const int*)d_in[6];
  const int* kofs0   = (const int*)d_in[7];
  const int* parent1 = (const int*)d_in[8];
  const int* kofs1   = (const int*)d_in[9];
  const int* parent2 = (const int*)d_in[10];
  const int* kofs2   = (const int*)d_in[11];
  const int N1 = in_sizes[6];
  const int N2 = in_sizes[8];
  const int N3 = in_sizes[10];
  const int ne0 = in_sizes[0], ne1 = in_sizes[1], ne2 = in_sizes[2];

  char* w = (char*)d_ws;
  auto carve = [&](size_t bytes) {
    char* p = w;
    w += (bytes + 255) & ~(size_t)255;
    return p;
  };
  _Float16* WgT = (_Float16*)carve((size_t)KNUM * 256 * 128 * 2);
  _Float16* WcT = (_Float16*)carve((size_t)KNUM * 64 * 64 * 2);
  int* ctrs     = (int*)carve(6 * KNUM * sizeof(int));   // counts[24] | cursor[24]
  int* counts   = ctrs;
  int* cursor   = ctrs + 3 * KNUM;
  _Float16* x0f = (_Float16*)carve((size_t)ne0 * 2);
  _Float16* x1f = (_Float16*)carve((size_t)ne1 * 2);
  _Float16* x2f = (_Float16*)carve((size_t)ne2 * 2);
  int* ord0     = (int*)carve((size_t)N1 * sizeof(int));
  int* por0     = (int*)carve((size_t)N1 * sizeof(int));
  int* ord1     = (int*)carve((size_t)N2 * sizeof(int));
  int* por1     = (int*)carve((size_t)N2 * sizeof(int));
  int* ord2     = (int*)carve((size_t)N3 * sizeof(int));
  int* por2     = (int*)carve((size_t)N3 * sizeof(int));
  _Float16* hc_a = (_Float16*)carve((size_t)N1 * 128 * 2);
  _Float16* hc_b = (_Float16*)carve((size_t)N2 * 128 * 2);
  (void)ws_size; (void)n_in; (void)out_size;

  hipMemsetAsync(ctrs, 0, 6 * KNUM * sizeof(int), stream);
  prep_kernel<<<1024, 256, 0, stream>>>(Wi, Wh, Wc, x0, x1, x2, ne0, ne1, ne2,
                                        kofs0, N1, kofs1, N2, kofs2, N3,
                                        WgT, WcT, x0f, x1f, x2f, counts);
  scatter_all_kernel<<<512, 256, 0, stream>>>(kofs0, parent0, N1, ord0, por0,
                                              kofs1, parent1, N2, ord1, por1,
                                              kofs2, parent2, N3, ord2, por2,
                                              counts, cursor);

  run_step<true, false>(x0f, nullptr, ord0, por0, N1, counts + 0 * KNUM,
                        WgT, WcT, nullptr, hc_a, stream);
  run_step<false, false>(x1f, hc_a, ord1, por1, N2, counts + 1 * KNUM,
                         WgT, WcT, nullptr, hc_b, stream);
  run_step<false, true>(x2f, hc_b, ord2, por2, N3, counts + 2 * KNUM,
                        WgT, WcT, (float*)d_out, nullptr, stream);
}

// Round 5
// 151.405 us; speedup vs baseline: 1.1274x; 1.1274x over previous
//
#include <hip/hip_runtime.h>

// Sparse generative transposed-conv LSTM decoder (3 timesteps).
// R5: R3's proven LDS+barrier step structure, plus two-level bucketing
// (k-offset major, parent-region minor) so per-tile gathers hit a ~320KB
// L2-resident window; bpk cap 256 for more resident blocks/CU; coalesced-read
// weight transpose; interleaved h|c state rows.
// Dispatches: memset, prep(+hist), scan, scatter, 3x step = 7.

#define KNUM 8
#define NREG 64          // parent regions per k-bucket
#define NBUK (KNUM * NREG)
#define TM 32            // rows per tile
#define STEP_THREADS 256

typedef __attribute__((ext_vector_type(8))) _Float16 f16x8;
typedef __attribute__((ext_vector_type(4))) float f32x4;

__device__ __forceinline__ float fsig(float x) {
  return __builtin_amdgcn_rcpf(1.0f + __expf(-x));
}
__device__ __forceinline__ float ftanh_(float x) {
  float e = __expf(2.0f * x);
  return 1.0f - 2.0f * __builtin_amdgcn_rcpf(e + 1.0f);
}
__device__ __forceinline__ f16x8 to_h8(float4 a, float4 b) {
  f16x8 r;
  r[0] = (_Float16)a.x; r[1] = (_Float16)a.y; r[2] = (_Float16)a.z; r[3] = (_Float16)a.w;
  r[4] = (_Float16)b.x; r[5] = (_Float16)b.y; r[6] = (_Float16)b.z; r[7] = (_Float16)b.w;
  return r;
}

// ---- prep: transpose+cast weights (coalesced reads), cast x to f16,
//      histogram (k,region) keys for all 3 segments ----
__global__ void prep_kernel(const float* __restrict__ Wi, const float* __restrict__ Wh,
                            const float* __restrict__ Wc,
                            const float* __restrict__ x0, const float* __restrict__ x1,
                            const float* __restrict__ x2, int ne0, int ne1, int ne2,
                            const int* __restrict__ k0, const int* __restrict__ p0, int n0,
                            const int* __restrict__ k1, const int* __restrict__ p1, int n1,
                            const int* __restrict__ k2, const int* __restrict__ p2, int n2,
                            int s0, int s1, int s2,
                            _Float16* __restrict__ WgT, _Float16* __restrict__ WcT,
                            _Float16* __restrict__ x0f, _Float16* __restrict__ x1f,
                            _Float16* __restrict__ x2f, int* __restrict__ counts) {
  __shared__ int hist[3 * NBUK];
  for (int i = threadIdx.x; i < 3 * NBUK; i += blockDim.x) hist[i] = 0;
  __syncthreads();
  int tid = blockIdx.x * blockDim.x + threadIdx.x;
  int stride = gridDim.x * blockDim.x;
  // WgT[k][co][ci]: ci<64 -> W_h, else W_i. co fastest -> coalesced source reads.
  for (int idx = tid; idx < KNUM * 128 * 256; idx += stride) {
    int k  = idx >> 15;
    int ci = (idx >> 8) & 127;
    int co = idx & 255;
    float v = (ci < 64) ? Wh[(k * 64 + ci) * 256 + co]
                        : Wi[(k * 64 + ci - 64) * 256 + co];
    WgT[((size_t)k * 256 + co) * 128 + ci] = (_Float16)v;
  }
  for (int idx = tid; idx < KNUM * 64 * 64; idx += stride) {
    int k  = idx >> 12;
    int ci = (idx >> 6) & 63;
    int co = idx & 63;
    WcT[((size_t)k * 64 + co) * 64 + ci] = (_Float16)Wc[(k * 64 + ci) * 64 + co];
  }
  for (int i = tid; i < (ne0 >> 3); i += stride) {
    float4 a = ((const float4*)x0)[2 * i], b = ((const float4*)x0)[2 * i + 1];
    ((f16x8*)x0f)[i] = to_h8(a, b);
  }
  for (int i = tid; i < (ne1 >> 3); i += stride) {
    float4 a = ((const float4*)x1)[2 * i], b = ((const float4*)x1)[2 * i + 1];
    ((f16x8*)x1f)[i] = to_h8(a, b);
  }
  for (int i = tid; i < (ne2 >> 3); i += stride) {
    float4 a = ((const float4*)x2)[2 * i], b = ((const float4*)x2)[2 * i + 1];
    ((f16x8*)x2f)[i] = to_h8(a, b);
  }
  // histograms over key = k*64 + min(parent>>shift, 63)
  for (int i = tid; i < n0; i += stride)
    atomicAdd(&hist[k0[i] * NREG + min(p0[i] >> s0, NREG - 1)], 1);
  for (int i = tid; i < n1; i += stride)
    atomicAdd(&hist[NBUK + k1[i] * NREG + min(p1[i] >> s1, NREG - 1)], 1);
  for (int i = tid; i < n2; i += stride)
    atomicAdd(&hist[2 * NBUK + k2[i] * NREG + min(p2[i] >> s2, NREG - 1)], 1);
  __syncthreads();
  for (int i = threadIdx.x; i < 3 * NBUK; i += blockDim.x)
    if (hist[i]) atomicAdd(&counts[i], hist[i]);
}

// ---- exclusive scan per segment (512 entries each) ----
__global__ void scan_kernel(const int* __restrict__ counts, int* __restrict__ offsets) {
  __shared__ int buf[NBUK];
  for (int s = 0; s < 3; ++s) {
    int v = counts[s * NBUK + threadIdx.x];
    buf[threadIdx.x] = v;
    __syncthreads();
    int sum = v;
    for (int d = 1; d < NBUK; d <<= 1) {
      int add = (threadIdx.x >= (unsigned)d) ? buf[threadIdx.x - d] : 0;
      __syncthreads();
      sum += add;
      buf[threadIdx.x] = sum;
      __syncthreads();
    }
    offsets[s * NBUK + threadIdx.x] = sum - v;  // exclusive
    __syncthreads();
  }
}

// ---- scatter into (k,region)-sorted order ----
__device__ __forceinline__ void seg_select(int b, int& seg, int& rb, int& nb) {
  if (b < 32)       { seg = 0; rb = b;       nb = 32;  }
  else if (b < 160) { seg = 1; rb = b - 32;  nb = 128; }
  else              { seg = 2; rb = b - 160; nb = 352; }
}

__global__ void scatter_all_kernel(const int* __restrict__ k0, const int* __restrict__ p0, int n0,
                                   int* __restrict__ o0, int* __restrict__ q0,
                                   const int* __restrict__ k1, const int* __restrict__ p1, int n1,
                                   int* __restrict__ o1, int* __restrict__ q1,
                                   const int* __restrict__ k2, const int* __restrict__ p2, int n2,
                                   int* __restrict__ o2, int* __restrict__ q2,
                                   int s0, int s1, int s2,
                                   const int* __restrict__ offsets, int* __restrict__ cursor) {
  int seg, rb, nb;
  seg_select(blockIdx.x, seg, rb, nb);
  const int* kp = seg == 0 ? k0 : seg == 1 ? k1 : k2;
  const int* pp = seg == 0 ? p0 : seg == 1 ? p1 : p2;
  int n  = seg == 0 ? n0 : seg == 1 ? n1 : n2;
  int sh = seg == 0 ? s0 : seg == 1 ? s1 : s2;
  int* order  = seg == 0 ? o0 : seg == 1 ? o1 : o2;
  int* porder = seg == 0 ? q0 : seg == 1 ? q1 : q2;

  __shared__ int h[NBUK], base[NBUK];
  for (int i = threadIdx.x; i < NBUK; i += blockDim.x) h[i] = 0;
  __syncthreads();
  int chunk = (n + nb - 1) / nb;
  int c0 = rb * chunk;
  int c1 = min(n, c0 + chunk);
  for (int i = c0 + threadIdx.x; i < c1; i += blockDim.x) {
    int b = kp[i] * NREG + min(pp[i] >> sh, NREG - 1);
    atomicAdd(&h[b], 1);
  }
  __syncthreads();
  for (int b = threadIdx.x; b < NBUK; b += blockDim.x) {
    base[b] = offsets[seg * NBUK + b] +
              (h[b] ? atomicAdd(&cursor[seg * NBUK + b], h[b]) : 0);
    h[b] = 0;
  }
  __syncthreads();
  for (int i = c0 + threadIdx.x; i < c1; i += blockDim.x) {
    int b = kp[i] * NREG + min(pp[i] >> sh, NREG - 1);
    int pos = base[b] + atomicAdd(&h[b], 1);
    order[pos] = i;          // bucket order nondeterministic; output row-indexed -> deterministic
    porder[pos] = pp[i];
  }
}

// ---- fused pipelined step kernel (R3 structure, offsets-based) ----
// 256 threads = 4 waves; wave w = 16-channel slice. TM=32 rows/tile.
// idx prefetched 2 tiles ahead; row gathers issue right after the LDS-write
// barrier (cover = MFMA + epilogue); staged regs drained at next top barrier.
template <bool FIRST, bool LAST>
__global__ __launch_bounds__(STEP_THREADS)
void lstm_step_kernel(const _Float16* __restrict__ xf, const _Float16* __restrict__ hc_in,
                      const int* __restrict__ order, const int* __restrict__ porder,
                      const int* __restrict__ offsets, int n,
                      const _Float16* __restrict__ WgT, const _Float16* __restrict__ WcT,
                      float* __restrict__ out32, _Float16* __restrict__ hc_out, int bpk) {
  __shared__ __align__(16) _Float16 A[TM][136];   // [h(0:64)|x(64:128)] + pad
  __shared__ __align__(16) _Float16 Cg[TM][72];
  __shared__ int jidx[TM];

  const int kb = blockIdx.x & 7;
  const int bi = blockIdx.x >> 3;
  const int off = offsets[kb * NREG];
  const int nxt = (kb < KNUM - 1) ? offsets[(kb + 1) * NREG] : n;
  const int cnt = nxt - off;
  const int ntiles = (cnt + TM - 1) / TM;
  if (bi >= ntiles) return;

  const int lane = threadIdx.x & 63;
  const int wc   = threadIdx.x >> 6;   // 16-channel slice
  const int l15  = lane & 15;
  const int kg   = lane >> 4;

  // B fragments in registers, once per block
  f16x8 bg[4][4];
  f16x8 bc[2];
  {
    const _Float16* wgp = WgT + (size_t)kb * (256 * 128);
#pragma unroll
    for (int g = 0; g < 4; ++g)
#pragma unroll
      for (int ks = (FIRST ? 2 : 0); ks < 4; ++ks)
        bg[g][ks] = *(const f16x8*)(wgp + (size_t)(64 * g + 16 * wc + l15) * 128 + ks * 32 + kg * 8);
    if constexpr (!FIRST) {
      const _Float16* wcp = WcT + (size_t)kb * (64 * 64);
#pragma unroll
      for (int ks = 0; ks < 2; ++ks)
        bc[ks] = *(const f16x8*)(wcp + (size_t)(16 * wc + l15) * 64 + ks * 32 + kg * 8);
    }
  }

  const int gr  = threadIdx.x >> 3;  // gather row 0..31
  const int gq8 = threadIdx.x & 7;   // 8-f16 slice

  int cj, cp; bool cv;   // current tile indices (resident)
  int nj, np; bool nv;   // next tile indices (prefetched)
  f16x8 sx{}, sh{}, sc{};

  auto idx_load = [&](int tt, int& j_, int& p_, bool& v_) {
    int grow = tt * TM + gr;
    v_ = (tt < ntiles) && (grow < cnt);
    j_ = -1; p_ = 0;
    if (v_) {
      if (gq8 == 0) j_ = order[off + grow];
      p_ = porder[off + grow];
    }
  };
  auto rows_load = [&](int p_, bool v_) {
    if (v_) {
      sx = *(const f16x8*)(xf + (size_t)p_ * 64 + gq8 * 8);
      if constexpr (!FIRST) {
        const _Float16* hr = hc_in + (size_t)p_ * 128 + gq8 * 8;
        sh = *(const f16x8*)(hr);
        sc = *(const f16x8*)(hr + 64);
      }
    } else {
      sx = f16x8{};
      if constexpr (!FIRST) { sh = f16x8{}; sc = f16x8{}; }
    }
  };

  idx_load(bi, cj, cp, cv);
  rows_load(cp, cv);
  idx_load(bi + bpk, nj, np, nv);

  for (int t = bi; t < ntiles; t += bpk) {
    __syncthreads();  // prev tile's LDS readers done; staged loads drained here
    if (gq8 == 0) jidx[gr] = cj;
    *(f16x8*)&A[gr][64 + gq8 * 8] = sx;
    if constexpr (!FIRST) {
      *(f16x8*)&A[gr][gq8 * 8]  = sh;
      *(f16x8*)&Cg[gr][gq8 * 8] = sc;
    }
    __syncthreads();

    // issue next tile's gathers now (idx resident); prefetch idx t+2
    rows_load(np, nv);
    cj = nj;
    idx_load(t + 2 * bpk, nj, np, nv);

    // MFMA: gates [32x256], c_up [32x64]
    f32x4 aG[2][4];
    f32x4 aC[2];
#pragma unroll
    for (int rf = 0; rf < 2; ++rf) {
#pragma unroll
      for (int g = 0; g < 4; ++g) aG[rf][g] = f32x4{0.f, 0.f, 0.f, 0.f};
      aC[rf] = f32x4{0.f, 0.f, 0.f, 0.f};
    }
#pragma unroll
    for (int ks = (FIRST ? 2 : 0); ks < 4; ++ks) {
#pragma unroll
      for (int rf = 0; rf < 2; ++rf) {
        f16x8 a = *(const f16x8*)&A[16 * rf + l15][ks * 32 + kg * 8];
        aG[rf][0] = __builtin_amdgcn_mfma_f32_16x16x32_f16(a, bg[0][ks], aG[rf][0], 0, 0, 0);
        aG[rf][1] = __builtin_amdgcn_mfma_f32_16x16x32_f16(a, bg[1][ks], aG[rf][1], 0, 0, 0);
        aG[rf][2] = __builtin_amdgcn_mfma_f32_16x16x32_f16(a, bg[2][ks], aG[rf][2], 0, 0, 0);
        aG[rf][3] = __builtin_amdgcn_mfma_f32_16x16x32_f16(a, bg[3][ks], aG[rf][3], 0, 0, 0);
      }
    }
    if constexpr (!FIRST) {
#pragma unroll
      for (int ks = 0; ks < 2; ++ks) {
#pragma unroll
        for (int rf = 0; rf < 2; ++rf) {
          f16x8 a = *(const f16x8*)&Cg[16 * rf + l15][ks * 32 + kg * 8];
          aC[rf] = __builtin_amdgcn_mfma_f32_16x16x32_f16(a, bc[ks], aC[rf], 0, 0, 0);
        }
      }
    }

    // LSTM epilogue + scatter store
#pragma unroll
    for (int rf = 0; rf < 2; ++rf) {
#pragma unroll
      for (int r = 0; r < 4; ++r) {
        int row = 16 * rf + kg * 4 + r;  // C/D: row=(lane>>4)*4+reg, col=lane&15
        int j = jidx[row];
        if (j < 0) continue;
        float ing = fsig(aG[rf][0][r]);
        float fg  = fsig(aG[rf][1][r]);
        float cgt = fsig(aG[rf][2][r]);   // reference uses sigmoid for cell gate
        float og  = fsig(aG[rf][3][r]);
        float cup = FIRST ? 0.0f : aC[rf][r];
        float cxv = fg * cup + ing * cgt;
        float hxv = og * ftanh_(cxv);
        int ch = 16 * wc + l15;
        if constexpr (LAST) {
          out32[(size_t)j * 64 + ch] = hxv;
        } else {
          hc_out[(size_t)j * 128 + ch]      = (_Float16)hxv;
          hc_out[(size_t)j * 128 + 64 + ch] = (_Float16)cxv;
        }
      }
    }
  }
}

static inline int idiv_up(int a, int b) { return (a + b - 1) / b; }

template <bool FIRST, bool LAST>
static void run_step(const _Float16* xf, const _Float16* hc_in,
                     const int* order, const int* porder, int nout, const int* offsets,
                     const _Float16* WgT, const _Float16* WcT,
                     float* out32, _Float16* hc_out, hipStream_t stream) {
  int bpk = idiv_up(nout, KNUM * TM);
  if (bpk > 256) bpk = 256;
  if (bpk < 1) bpk = 1;
  lstm_step_kernel<FIRST, LAST><<<dim3(KNUM * bpk), dim3(STEP_THREADS), 0, stream>>>(
      xf, hc_in, order, porder, offsets, nout, WgT, WcT, out32, hc_out, bpk);
}

extern "C" void kernel_launch(void* const* d_in, const int* in_sizes, int n_in,
                              void* d_out, int out_size, void* d_ws, size_t ws_size,
                              hipStream_t stream) {
  const float* x0 = (const float*)d_in[0];
  const float* x1 = (const float*)d_in[1];
  const float* x2 = (const float*)d_in[2];
  const float* Wi = (const float*)d_in[3];
  const float* Wh = (const float*)d_in[4];
  const float* Wc = (const float*)d_in[5];
  const int* parent0 = (const int*)d_in[6];
  const int* kofs0   = (const int*)d_in[7];
  const int* parent1 = (const int*)d_in[8];
  const int* kofs1   = (const int*)d_in[9];
  const int* parent2 = (const int*)d_in[10];
  const int* kofs2   = (const int*)d_in[11];
  const int N1 = in_sizes[6];
  const int N2 = in_sizes[8];
  const int N3 = in_sizes[10];
  const int ne0 = in_sizes[0], ne1 = in_sizes[1], ne2 = in_sizes[2];
  const int nin0 = ne0 / 64, nin1 = ne1 / 64, nin2 = ne2 / 64;

  auto shf = [](int nin) { int s = 0; while ((nin >> s) > NREG) ++s; return s; };
  const int s0 = shf(nin0), s1 = shf(nin1), s2 = shf(nin2);

  char* w = (char*)d_ws;
  auto carve = [&](size_t bytes) {
    char* p = w;
    w += (bytes + 255) & ~(size_t)255;
    return p;
  };
  _Float16* WgT = (_Float16*)carve((size_t)KNUM * 256 * 128 * 2);
  _Float16* WcT = (_Float16*)carve((size_t)KNUM * 64 * 64 * 2);
  int* ctrs     = (int*)carve(6 * NBUK * sizeof(int));   // counts[3*512] | cursor[3*512]
  int* counts   = ctrs;
  int* cursor   = ctrs + 3 * NBUK;
  int* offsets  = (int*)carve(3 * NBUK * sizeof(int));
  _Float16* x0f = (_Float16*)carve((size_t)ne0 * 2);
  _Float16* x1f = (_Float16*)carve((size_t)ne1 * 2);
  _Float16* x2f = (_Float16*)carve((size_t)ne2 * 2);
  int* ord0     = (int*)carve((size_t)N1 * sizeof(int));
  int* por0     = (int*)carve((size_t)N1 * sizeof(int));
  int* ord1     = (int*)carve((size_t)N2 * sizeof(int));
  int* por1     = (int*)carve((size_t)N2 * sizeof(int));
  int* ord2     = (int*)carve((size_t)N3 * sizeof(int));
  int* por2     = (int*)carve((size_t)N3 * sizeof(int));
  _Float16* hc_a = (_Float16*)carve((size_t)N1 * 128 * 2);
  _Float16* hc_b = (_Float16*)carve((size_t)N2 * 128 * 2);
  (void)ws_size; (void)n_in; (void)out_size;

  hipMemsetAsync(ctrs, 0, 6 * NBUK * sizeof(int), stream);
  prep_kernel<<<1024, 256, 0, stream>>>(Wi, Wh, Wc, x0, x1, x2, ne0, ne1, ne2,
                                        kofs0, parent0, N1, kofs1, parent1, N2,
                                        kofs2, parent2, N3, s0, s1, s2,
                                        WgT, WcT, x0f, x1f, x2f, counts);
  scan_kernel<<<1, NBUK, 0, stream>>>(counts, offsets);
  scatter_all_kernel<<<512, 256, 0, stream>>>(kofs0, parent0, N1, ord0, por0,
                                              kofs1, parent1, N2, ord1, por1,
                                              kofs2, parent2, N3, ord2, por2,
                                              s0, s1, s2, offsets, cursor);

  run_step<true, false>(x0f, nullptr, ord0, por0, N1, offsets + 0 * NBUK,
                        WgT, WcT, nullptr, hc_a, stream);
  run_step<false, false>(x1f, hc_a, ord1, por1, N2, offsets + 1 * NBUK,
                         WgT, WcT, nullptr, hc_b, stream);
  run_step<false, true>(x2f, hc_b, ord2, por2, N3, offsets + 2 * NBUK,
                        WgT, WcT, (float*)d_out, nullptr, stream);
}

// Round 6
// 122.429 us; speedup vs baseline: 1.3942x; 1.2367x over previous
//
#include <hip/hip_runtime.h>

// Sparse generative transposed-conv LSTM decoder (3 timesteps).
// R6: R3 structure + bare s_barrier (no vmcnt drain) + 2-deep named-register
// row staging (rows issued ~2 tiles ahead -> HBM latency fully covered).
// k-only bucketing, int2-packed {order,parent}, interleaved h|c state rows.
// Dispatches: memset, prep(+hist), scatter, 3x step = 6.

#define KNUM 8
#define TM 32
#define STEP_THREADS 256

typedef __attribute__((ext_vector_type(8))) _Float16 f16x8;
typedef __attribute__((ext_vector_type(4))) float f32x4;

__device__ __forceinline__ float fsig(float x) {
  return __builtin_amdgcn_rcpf(1.0f + __expf(-x));
}
__device__ __forceinline__ float ftanh_(float x) {
  float e = __expf(2.0f * x);
  return 1.0f - 2.0f * __builtin_amdgcn_rcpf(e + 1.0f);
}
__device__ __forceinline__ f16x8 to_h8(float4 a, float4 b) {
  f16x8 r;
  r[0] = (_Float16)a.x; r[1] = (_Float16)a.y; r[2] = (_Float16)a.z; r[3] = (_Float16)a.w;
  r[4] = (_Float16)b.x; r[5] = (_Float16)b.y; r[6] = (_Float16)b.z; r[7] = (_Float16)b.w;
  return r;
}

// ---- prep: transpose+cast weights (coalesced writes, L2 absorbs the
//      strided re-reads), cast x to f16, k-histograms ----
__global__ void prep_kernel(const float* __restrict__ Wi, const float* __restrict__ Wh,
                            const float* __restrict__ Wc,
                            const float* __restrict__ x0, const float* __restrict__ x1,
                            const float* __restrict__ x2, int ne0, int ne1, int ne2,
                            const int* __restrict__ k0, int n0,
                            const int* __restrict__ k1, int n1,
                            const int* __restrict__ k2, int n2,
                            _Float16* __restrict__ WgT, _Float16* __restrict__ WcT,
                            _Float16* __restrict__ x0f, _Float16* __restrict__ x1f,
                            _Float16* __restrict__ x2f, int* __restrict__ counts) {
  __shared__ int sh[3 * KNUM];
  if (threadIdx.x < 3 * KNUM) sh[threadIdx.x] = 0;
  __syncthreads();
  int tid = blockIdx.x * blockDim.x + threadIdx.x;
  int stride = gridDim.x * blockDim.x;
  // WgT[k][co][ci]: ci<64 -> W_h, else W_i (f16). ci fastest -> coalesced writes.
  for (int idx = tid; idx < KNUM * 256 * 128; idx += stride) {
    int k  = idx >> 15;
    int co = (idx >> 7) & 255;
    int ci = idx & 127;
    float v = (ci < 64) ? Wh[(k * 64 + ci) * 256 + co]
                        : Wi[(k * 64 + ci - 64) * 256 + co];
    WgT[idx] = (_Float16)v;
  }
  for (int idx = tid; idx < KNUM * 64 * 64; idx += stride) {
    int k  = idx >> 12;
    int co = (idx >> 6) & 63;
    int ci = idx & 63;
    WcT[idx] = (_Float16)Wc[(k * 64 + ci) * 64 + co];
  }
  for (int i = tid; i < (ne0 >> 3); i += stride) {
    float4 a = ((const float4*)x0)[2 * i], b = ((const float4*)x0)[2 * i + 1];
    ((f16x8*)x0f)[i] = to_h8(a, b);
  }
  for (int i = tid; i < (ne1 >> 3); i += stride) {
    float4 a = ((const float4*)x1)[2 * i], b = ((const float4*)x1)[2 * i + 1];
    ((f16x8*)x1f)[i] = to_h8(a, b);
  }
  for (int i = tid; i < (ne2 >> 3); i += stride) {
    float4 a = ((const float4*)x2)[2 * i], b = ((const float4*)x2)[2 * i + 1];
    ((f16x8*)x2f)[i] = to_h8(a, b);
  }
  for (int i = tid; i < n0; i += stride) atomicAdd(&sh[k0[i]], 1);
  for (int i = tid; i < n1; i += stride) atomicAdd(&sh[KNUM + k1[i]], 1);
  for (int i = tid; i < n2; i += stride) atomicAdd(&sh[2 * KNUM + k2[i]], 1);
  __syncthreads();
  if (threadIdx.x < 3 * KNUM && sh[threadIdx.x]) atomicAdd(&counts[threadIdx.x], sh[threadIdx.x]);
}

// ---- scatter into k-sorted order; op[pos] = {orig_row, parent} ----
__device__ __forceinline__ void seg_select(int b, int& seg, int& rb, int& nb) {
  if (b < 32)       { seg = 0; rb = b;       nb = 32;  }
  else if (b < 160) { seg = 1; rb = b - 32;  nb = 128; }
  else              { seg = 2; rb = b - 160; nb = 352; }
}

__global__ void scatter_all_kernel(const int* __restrict__ k0, const int* __restrict__ p0, int n0,
                                   int2* __restrict__ op0,
                                   const int* __restrict__ k1, const int* __restrict__ p1, int n1,
                                   int2* __restrict__ op1,
                                   const int* __restrict__ k2, const int* __restrict__ p2, int n2,
                                   int2* __restrict__ op2,
                                   const int* __restrict__ counts, int* __restrict__ cursor) {
  int seg, rb, nb;
  seg_select(blockIdx.x, seg, rb, nb);
  const int* kp = seg == 0 ? k0 : seg == 1 ? k1 : k2;
  const int* pp = seg == 0 ? p0 : seg == 1 ? p1 : p2;
  int n = seg == 0 ? n0 : seg == 1 ? n1 : n2;
  int2* op = seg == 0 ? op0 : seg == 1 ? op1 : op2;

  __shared__ int h[KNUM], base[KNUM];
  if (threadIdx.x < KNUM) h[threadIdx.x] = 0;
  __syncthreads();
  int chunk = (n + nb - 1) / nb;
  int c0 = rb * chunk;
  int c1 = min(n, c0 + chunk);
  for (int i = c0 + threadIdx.x; i < c1; i += blockDim.x)
    atomicAdd(&h[kp[i]], 1);
  __syncthreads();
  if (threadIdx.x < KNUM) {
    int offk = 0;
    for (int k = 0; k < (int)threadIdx.x; ++k) offk += counts[seg * KNUM + k];
    base[threadIdx.x] = offk + atomicAdd(&cursor[seg * KNUM + threadIdx.x], h[threadIdx.x]);
    h[threadIdx.x] = 0;
  }
  __syncthreads();
  for (int i = c0 + threadIdx.x; i < c1; i += blockDim.x) {
    int k = kp[i];
    int pos = base[k] + atomicAdd(&h[k], 1);
    op[pos] = make_int2(i, pp[i]);  // bucket order nondeterministic; output row-indexed -> deterministic
  }
}

// ---- step kernel: bare barriers + 2-deep named-set row staging ----
// 256 threads = 4 waves; wave = 16-channel slice. TM=32 rows/tile.
// Invariant entering the handling of tile t with set S: S holds rows(t),
// and jpP holds indices of tile t+2*bpk. Rows for t+2*bpk are issued right
// after the LDS write of tile t -> ~2 full tiles of latency cover, and no
// vmcnt(0) drain anywhere in the loop (bare s_barrier).
template <bool FIRST, bool LAST>
__global__ __launch_bounds__(STEP_THREADS)
void lstm_step_kernel(const _Float16* __restrict__ xf, const _Float16* __restrict__ hc_in,
                      const int2* __restrict__ op, const int* __restrict__ counts,
                      const _Float16* __restrict__ WgT, const _Float16* __restrict__ WcT,
                      float* __restrict__ out32, _Float16* __restrict__ hc_out, int bpk) {
  __shared__ __align__(16) _Float16 A[TM][136];   // [h(0:64)|x(64:128)] + pad
  __shared__ __align__(16) _Float16 Cg[TM][72];
  __shared__ int jidx[TM];

  const int kb = blockIdx.x & 7;
  const int bi = blockIdx.x >> 3;
  int cnt = 0, off = 0;
#pragma unroll
  for (int k = 0; k < KNUM; ++k) {
    int c = counts[k];
    if (k < kb) off += c;
    if (k == kb) cnt = c;
  }
  const int ntiles = (cnt + TM - 1) / TM;
  if (bi >= ntiles) return;

  const int lane = threadIdx.x & 63;
  const int wcq  = threadIdx.x >> 6;   // 16-channel slice
  const int l15  = lane & 15;
  const int kg   = lane >> 4;

  // B fragments in registers, once per block
  f16x8 bg[4][4];
  f16x8 bc[2];
  {
    const _Float16* wgp = WgT + (size_t)kb * (256 * 128);
#pragma unroll
    for (int g = 0; g < 4; ++g)
#pragma unroll
      for (int ks = (FIRST ? 2 : 0); ks < 4; ++ks)
        bg[g][ks] = *(const f16x8*)(wgp + (size_t)(64 * g + 16 * wcq + l15) * 128 + ks * 32 + kg * 8);
    if constexpr (!FIRST) {
      const _Float16* wcp = WcT + (size_t)kb * (64 * 64);
#pragma unroll
      for (int ks = 0; ks < 2; ++ks)
        bc[ks] = *(const f16x8*)(wcp + (size_t)(16 * wcq + l15) * 64 + ks * 32 + kg * 8);
    }
  }

  const int gr  = threadIdx.x >> 3;  // staging row 0..31
  const int gq8 = threadIdx.x & 7;   // 8-f16 slice

  auto idx_of = [&](int tt) -> int2 {
    int grow = tt * TM + gr;
    bool v = (tt < ntiles) && (grow < cnt);
    int2 jp = op[off + min(grow, cnt - 1)];   // clamped, unconditional
    if (!v) jp.x = -1;
    return jp;
  };

  // named 2-deep staging sets (no runtime indexing -> stays in registers)
  f16x8 xA{}, hA{}, cA{}; int jA = -1;
  f16x8 xB{}, hB{}, cB{}; int jB = -1;
  int2 jpP;

  auto rows_into = [&](int2 jp, f16x8& rx, f16x8& rh, f16x8& rc, int& rj) {
    int p = jp.y;
    rx = *(const f16x8*)(xf + (size_t)p * 64 + gq8 * 8);
    if constexpr (!FIRST) {
      const _Float16* hr = hc_in + (size_t)p * 128 + gq8 * 8;
      rh = *(const f16x8*)(hr);
      rc = *(const f16x8*)(hr + 64);
    }
    rj = jp.x;
  };

  // prologue: stage tiles bi and bi+bpk; prefetch indices of bi+2*bpk
  rows_into(idx_of(bi), xA, hA, cA, jA);
  rows_into(idx_of(bi + bpk), xB, hB, cB, jB);
  jpP = idx_of(bi + 2 * bpk);

#define HALF_STEP(TCUR, RX, RH, RC, RJ)                                         \
  {                                                                             \
    asm volatile("s_barrier" ::: "memory");                                     \
    if (gq8 == 0) jidx[gr] = RJ;                                                \
    *(f16x8*)&A[gr][64 + gq8 * 8] = RX;                                         \
    if constexpr (!FIRST) {                                                     \
      *(f16x8*)&A[gr][gq8 * 8]  = RH;                                           \
      *(f16x8*)&Cg[gr][gq8 * 8] = RC;                                           \
    }                                                                           \
    asm volatile("s_waitcnt lgkmcnt(0)\n\ts_barrier" ::: "memory");             \
    rows_into(jpP, RX, RH, RC, RJ);      /* prefetch rows((TCUR)+2*bpk) */      \
    jpP = idx_of((TCUR) + 3 * bpk);      /* prefetch indices one stage ahead */ \
    f32x4 aG[2][4];                                                             \
    f32x4 aC[2];                                                                \
    _Pragma("unroll")                                                           \
    for (int rf = 0; rf < 2; ++rf) {                                            \
      _Pragma("unroll")                                                         \
      for (int g = 0; g < 4; ++g) aG[rf][g] = f32x4{0.f, 0.f, 0.f, 0.f};        \
      aC[rf] = f32x4{0.f, 0.f, 0.f, 0.f};                                       \
    }                                                                           \
    _Pragma("unroll")                                                           \
    for (int ks = (FIRST ? 2 : 0); ks < 4; ++ks) {                              \
      _Pragma("unroll")                                                         \
      for (int rf = 0; rf < 2; ++rf) {                                          \
        f16x8 a = *(const f16x8*)&A[16 * rf + l15][ks * 32 + kg * 8];           \
        aG[rf][0] = __builtin_amdgcn_mfma_f32_16x16x32_f16(a, bg[0][ks], aG[rf][0], 0, 0, 0); \
        aG[rf][1] = __builtin_amdgcn_mfma_f32_16x16x32_f16(a, bg[1][ks], aG[rf][1], 0, 0, 0); \
        aG[rf][2] = __builtin_amdgcn_mfma_f32_16x16x32_f16(a, bg[2][ks], aG[rf][2], 0, 0, 0); \
        aG[rf][3] = __builtin_amdgcn_mfma_f32_16x16x32_f16(a, bg[3][ks], aG[rf][3], 0, 0, 0); \
      }                                                                         \
    }                                                                           \
    if constexpr (!FIRST) {                                                     \
      _Pragma("unroll")                                                         \
      for (int ks = 0; ks < 2; ++ks) {                                          \
        _Pragma("unroll")                                                       \
        for (int rf = 0; rf < 2; ++rf) {                                        \
          f16x8 a = *(const f16x8*)&Cg[16 * rf + l15][ks * 32 + kg * 8];        \
          aC[rf] = __builtin_amdgcn_mfma_f32_16x16x32_f16(a, bc[ks], aC[rf], 0, 0, 0); \
        }                                                                       \
      }                                                                         \
    }                                                                           \
    _Pragma("unroll")                                                           \
    for (int rf = 0; rf < 2; ++rf) {                                            \
      _Pragma("unroll")                                                         \
      for (int r = 0; r < 4; ++r) {                                             \
        int row = 16 * rf + kg * 4 + r;                                         \
        int j = jidx[row];                                                      \
        if (j < 0) continue;                                                    \
        float ing = fsig(aG[rf][0][r]);                                         \
        float fg  = fsig(aG[rf][1][r]);                                         \
        float cgt = fsig(aG[rf][2][r]);                                         \
        float og  = fsig(aG[rf][3][r]);                                         \
        float cup = FIRST ? 0.0f : aC[rf][r];                                   \
        float cxv = fg * cup + ing * cgt;                                       \
        float hxv = og * ftanh_(cxv);                                           \
        int ch = 16 * wcq + l15;                                                \
        if constexpr (LAST) {                                                   \
          out32[(size_t)j * 64 + ch] = hxv;                                     \
        } else {                                                                \
          hc_out[(size_t)j * 128 + ch]      = (_Float16)hxv;                    \
          hc_out[(size_t)j * 128 + 64 + ch] = (_Float16)cxv;                    \
        }                                                                       \
      }                                                                         \
    }                                                                           \
  }

  for (int t = bi; t < ntiles; t += 2 * bpk) {
    HALF_STEP(t, xA, hA, cA, jA);
    if (t + bpk < ntiles) {
      HALF_STEP(t + bpk, xB, hB, cB, jB);
    }
  }
#undef HALF_STEP
}

static inline int idiv_up(int a, int b) { return (a + b - 1) / b; }

template <bool FIRST, bool LAST>
static void run_step(const _Float16* xf, const _Float16* hc_in,
                     const int2* op, int nout, const int* counts,
                     const _Float16* WgT, const _Float16* WcT,
                     float* out32, _Float16* hc_out, hipStream_t stream) {
  int bpk = idiv_up(nout, KNUM * TM);
  if (bpk > 128) bpk = 128;
  if (bpk < 1) bpk = 1;
  lstm_step_kernel<FIRST, LAST><<<dim3(KNUM * bpk), dim3(STEP_THREADS), 0, stream>>>(
      xf, hc_in, op, counts, WgT, WcT, out32, hc_out, bpk);
}

extern "C" void kernel_launch(void* const* d_in, const int* in_sizes, int n_in,
                              void* d_out, int out_size, void* d_ws, size_t ws_size,
                              hipStream_t stream) {
  const float* x0 = (const float*)d_in[0];
  const float* x1 = (const float*)d_in[1];
  const float* x2 = (const float*)d_in[2];
  const float* Wi = (const float*)d_in[3];
  const float* Wh = (const float*)d_in[4];
  const float* Wc = (const float*)d_in[5];
  const int* parent0 = (const int*)d_in[6];
  const int* kofs0   = (const int*)d_in[7];
  const int* parent1 = (const int*)d_in[8];
  const int* kofs1   = (const int*)d_in[9];
  const int* parent2 = (const int*)d_in[10];
  const int* kofs2   = (const int*)d_in[11];
  const int N1 = in_sizes[6];
  const int N2 = in_sizes[8];
  const int N3 = in_sizes[10];
  const int ne0 = in_sizes[0], ne1 = in_sizes[1], ne2 = in_sizes[2];

  char* w = (char*)d_ws;
  auto carve = [&](size_t bytes) {
    char* p = w;
    w += (bytes + 255) & ~(size_t)255;
    return p;
  };
  _Float16* WgT = (_Float16*)carve((size_t)KNUM * 256 * 128 * 2);
  _Float16* WcT = (_Float16*)carve((size_t)KNUM * 64 * 64 * 2);
  int* ctrs     = (int*)carve(6 * KNUM * sizeof(int));   // counts[24] | cursor[24]
  int* counts   = ctrs;
  int* cursor   = ctrs + 3 * KNUM;
  _Float16* x0f = (_Float16*)carve((size_t)ne0 * 2);
  _Float16* x1f = (_Float16*)carve((size_t)ne1 * 2);
  _Float16* x2f = (_Float16*)carve((size_t)ne2 * 2);
  int2* op0     = (int2*)carve((size_t)N1 * sizeof(int2));
  int2* op1     = (int2*)carve((size_t)N2 * sizeof(int2));
  int2* op2     = (int2*)carve((size_t)N3 * sizeof(int2));
  _Float16* hc_a = (_Float16*)carve((size_t)N1 * 128 * 2);
  _Float16* hc_b = (_Float16*)carve((size_t)N2 * 128 * 2);
  (void)ws_size; (void)n_in; (void)out_size;

  hipMemsetAsync(ctrs, 0, 6 * KNUM * sizeof(int), stream);
  prep_kernel<<<1024, 256, 0, stream>>>(Wi, Wh, Wc, x0, x1, x2, ne0, ne1, ne2,
                                        kofs0, N1, kofs1, N2, kofs2, N3,
                                        WgT, WcT, x0f, x1f, x2f, counts);
  scatter_all_kernel<<<512, 256, 0, stream>>>(kofs0, parent0, N1, op0,
                                              kofs1, parent1, N2, op1,
                                              kofs2, parent2, N3, op2,
                                              counts, cursor);

  run_step<true, false>(x0f, nullptr, op0, N1, counts + 0 * KNUM,
                        WgT, WcT, nullptr, hc_a, stream);
  run_step<false, false>(x1f, hc_a, op1, N2, counts + 1 * KNUM,
                         WgT, WcT, nullptr, hc_b, stream);
  run_step<false, true>(x2f, hc_b, op2, N3, counts + 2 * KNUM,
                        WgT, WcT, (float*)d_out, nullptr, stream);
}